// Round 3
// baseline (88.788 us; speedup 1.0000x reference)
//
#include <hip/hip_runtime.h>

// QLinear: y[n,o] = round((sum_k (x[n,k]-xz)*(w[o,k]-wz) + bias[o]) * M + yz)
// N=65536, K=512, OUT=512.
// Exact i8 path: (x-128),(w-128) in [-128,127]; |dot| <= 8.4M < 2^31; f32 epilogue exact.
// Two-pass: xprep (f32 -> i8, streams at HBM BW) then i8 GEMM whose reads are LLC-resident.

#define K_DIM 512
#define OUTF  512
#define NT    8                 // K-steps of 64

typedef __attribute__((ext_vector_type(4))) int i32x4;
typedef __attribute__((ext_vector_type(4))) float f32x4;
typedef __attribute__((ext_vector_type(4))) unsigned int u32x4;

__device__ __forceinline__ void gload16(const void* g, void* l) {
    __builtin_amdgcn_global_load_lds(
        (const __attribute__((address_space(1))) void*)g,
        (__attribute__((address_space(3))) void*)l,
        16, 0, 0);
}

// ---------- prepass: weight int32 -> i8 (w - wz) ----------
__global__ void wprep(const int* __restrict__ W, unsigned int* __restrict__ Wb,
                      const float* __restrict__ wzp) {
    const int wz = __float2int_rn(wzp[0]);
    int idx = (blockIdx.x * blockDim.x + threadIdx.x) * 4;
    i32x4 w = *reinterpret_cast<const i32x4*>(W + idx);
    unsigned int b0 = (unsigned int)(w[0] - wz) & 0xffu;
    unsigned int b1 = (unsigned int)(w[1] - wz) & 0xffu;
    unsigned int b2 = (unsigned int)(w[2] - wz) & 0xffu;
    unsigned int b3 = (unsigned int)(w[3] - wz) & 0xffu;
    Wb[idx >> 2] = b0 | (b1 << 8) | (b2 << 16) | (b3 << 24);
}

// ---------- prepass: x f32 -> i8 (x - xz) ----------
__global__ __launch_bounds__(256)
void xprep(const float* __restrict__ X, u32x4* __restrict__ Xb,
           const float* __restrict__ xzp) {
    const int xz = __float2int_rn(xzp[0]);
    size_t i = (size_t)blockIdx.x * blockDim.x + threadIdx.x;   // 16 floats each
    const f32x4* xp = reinterpret_cast<const f32x4*>(X) + i * 4;
    u32x4 o;
    #pragma unroll
    for (int q = 0; q < 4; ++q) {
        f32x4 v = xp[q];
        unsigned int b0 = (unsigned int)((int)v[0] - xz) & 0xffu;
        unsigned int b1 = (unsigned int)((int)v[1] - xz) & 0xffu;
        unsigned int b2 = (unsigned int)((int)v[2] - xz) & 0xffu;
        unsigned int b3 = (unsigned int)((int)v[3] - xz) & 0xffu;
        o[q] = b0 | (b1 << 8) | (b2 << 16) | (b3 << 24);
    }
    Xb[i] = o;
}

// ---------- main GEMM: i8 x i8, fragment-major LDS, global_load_lds ----------
// block = 256 threads (4 waves, 2x2), tile 128x128, BK=64.
// LDS per buffer: A = 8 frags x 64 lanes x 16B = 8KB, B same -> 16KB; x2 = 32KB.
__global__ __launch_bounds__(256, 4)
void qgemm(const unsigned char* __restrict__ Xb,
           const unsigned char* __restrict__ Wb,
           const int* __restrict__ bias,
           const float* __restrict__ Mp,
           const float* __restrict__ yzp,
           float* __restrict__ Y) {
    __shared__ unsigned char lds[2][16384];

    const int tid  = threadIdx.x;
    const int lane = tid & 63;
    const int wid  = tid >> 6;          // 0..3
    const int wr   = wid >> 1;          // wave row (64-strip)
    const int wc   = wid & 1;           // wave col (64-strip)
    const int fr   = lane & 15;
    const int fq   = lane >> 4;

    // XCD-contiguous bijective swizzle (2048 = 8 * 256)
    const int b = blockIdx.x;
    const int lid = (b & 7) * 256 + (b >> 3);
    const int row0 = (lid >> 2) * 128;
    const int n0   = (lid & 3) * 128;

    // staging: wave w stages A-frags {2w,2w+1} and B-frags {2w,2w+1}.
    // frag f holds rows f*16+(l&15), kbytes (l>>4)*16 — per-lane global addr,
    // lane-linear LDS dest (gload_lds constraint) == MFMA fragment order.
    const unsigned char* gA = Xb + (size_t)(row0 + wid * 32 + fr) * K_DIM + fq * 16;
    const unsigned char* gB = Wb + (size_t)(n0   + wid * 32 + fr) * K_DIM + fq * 16;
    const int ldsA = wid * 2048;            // frag 2w at f*1024
    const int ldsB = 8192 + wid * 2048;

    i32x4 acc[4][4] = {};

    auto stage = [&](int t, int buf) {
        const unsigned char* ga = gA + t * 64;
        const unsigned char* gb = gB + t * 64;
        gload16(ga,              &lds[buf][ldsA]);
        gload16(ga + 16 * K_DIM, &lds[buf][ldsA + 1024]);
        gload16(gb,              &lds[buf][ldsB]);
        gload16(gb + 16 * K_DIM, &lds[buf][ldsB + 1024]);
    };

    auto compute = [&](int buf) {
        i32x4 af[4], bf[4];
        #pragma unroll
        for (int m = 0; m < 4; ++m)
            af[m] = *reinterpret_cast<const i32x4*>(&lds[buf][(wr * 4 + m) * 1024 + lane * 16]);
        #pragma unroll
        for (int n = 0; n < 4; ++n)
            bf[n] = *reinterpret_cast<const i32x4*>(&lds[buf][8192 + (wc * 4 + n) * 1024 + lane * 16]);
        #pragma unroll
        for (int m = 0; m < 4; ++m)
            #pragma unroll
            for (int n = 0; n < 4; ++n)
                acc[m][n] = __builtin_amdgcn_mfma_i32_16x16x64_i8(
                    af[m], bf[n], acc[m][n], 0, 0, 0);
    };

    stage(0, 0);
    __syncthreads();                        // drains vmcnt: buf0 ready

    #pragma unroll
    for (int t = 0; t < NT; ++t) {
        if (t < NT - 1) stage(t + 1, (t + 1) & 1);   // issue next tile first
        compute(t & 1);
        __syncthreads();                    // drains stage(t+1) + ds_reads
    }

    // epilogue: y = rintf((acc + bias) * M + yz)
    const float M = Mp[0], yz = yzp[0];
    #pragma unroll
    for (int n = 0; n < 4; ++n) {
        const int col = n0 + wc * 64 + n * 16 + fr;
        const int bv = bias[col];
        #pragma unroll
        for (int m = 0; m < 4; ++m) {
            const int row = row0 + wr * 64 + m * 16 + fq * 4;
            float* yp = Y + (size_t)row * OUTF + col;
            #pragma unroll
            for (int j = 0; j < 4; ++j)
                yp[(size_t)j * OUTF] = rintf((float)(acc[m][n][j] + bv) * M + yz);
        }
    }
}

// ---------- fallback (ws too small): R2 single-pass kernel ----------
#define LDAB  80
#define TILE_B (128 * LDAB)
#define BUF_B  (2 * TILE_B)

__global__ __launch_bounds__(512, 4)
void qgemm_fb(const float* __restrict__ X,
              const unsigned char* __restrict__ Wb,
              const int* __restrict__ bias,
              const float* __restrict__ Mp,
              const float* __restrict__ xzp,
              const float* __restrict__ yzp,
              float* __restrict__ Y) {
    __shared__ unsigned char lds[2 * BUF_B];

    const int tid  = threadIdx.x;
    const int lane = tid & 63;
    const int wid  = tid >> 6;
    const int wr   = wid >> 2;
    const int wc   = wid & 3;
    const int fr   = lane & 15;
    const int fq   = lane >> 4;

    const int b = blockIdx.x;
    const int lid = (b & 7) * 256 + (b >> 3);
    const int row0 = (lid >> 2) * 128;
    const int n0   = (lid & 3) * 128;

    const int xz = __float2int_rn(xzp[0]);

    const int srow = tid >> 2;
    const int scol = (tid & 3) * 16;
    const float* xbase = X + (size_t)(row0 + srow) * K_DIM + scol;
    const unsigned char* wbase = Wb + (size_t)(n0 + srow) * K_DIM + scol;
    const int aoff = srow * LDAB + scol;
    const int boff = TILE_B + srow * LDAB + scol;

    f32x4 ra[4];
    i32x4 rb;

    auto stage = [&](int t) {
        const float* xp = xbase + t * 64;
        #pragma unroll
        for (int q = 0; q < 4; ++q)
            ra[q] = *reinterpret_cast<const f32x4*>(xp + q * 4);
        rb = *reinterpret_cast<const i32x4*>(wbase + t * 64);
    };
    auto convwrite = [&](int buf) {
        const int ab = buf * BUF_B;
        i32x4 pa;
        #pragma unroll
        for (int q = 0; q < 4; ++q) {
            unsigned int b0 = (unsigned int)((int)ra[q][0] - xz) & 0xffu;
            unsigned int b1 = (unsigned int)((int)ra[q][1] - xz) & 0xffu;
            unsigned int b2 = (unsigned int)((int)ra[q][2] - xz) & 0xffu;
            unsigned int b3 = (unsigned int)((int)ra[q][3] - xz) & 0xffu;
            pa[q] = (int)(b0 | (b1 << 8) | (b2 << 16) | (b3 << 24));
        }
        *reinterpret_cast<i32x4*>(&lds[ab + aoff]) = pa;
        *reinterpret_cast<i32x4*>(&lds[ab + boff]) = rb;
    };

    i32x4 acc[4][2] = {};
    const int aro = (wr * 64 + fr) * LDAB + fq * 16;
    const int bro = TILE_B + (wc * 32 + fr) * LDAB + fq * 16;

    auto compute = [&](int buf) {
        const int ab = buf * BUF_B;
        i32x4 af[4], bf[2];
        #pragma unroll
        for (int m = 0; m < 4; ++m)
            af[m] = *reinterpret_cast<const i32x4*>(&lds[ab + aro + m * 16 * LDAB]);
        #pragma unroll
        for (int n = 0; n < 2; ++n)
            bf[n] = *reinterpret_cast<const i32x4*>(&lds[ab + bro + n * 16 * LDAB]);
        #pragma unroll
        for (int m = 0; m < 4; ++m)
            #pragma unroll
            for (int n = 0; n < 2; ++n)
                acc[m][n] = __builtin_amdgcn_mfma_i32_16x16x64_i8(
                    af[m], bf[n], acc[m][n], 0, 0, 0);
    };

    stage(0);
    convwrite(0);
    __syncthreads();

    #pragma unroll
    for (int t = 0; t < NT; ++t) {
        if (t < NT - 1) stage(t + 1);
        compute(t & 1);
        if (t < NT - 1) convwrite((t + 1) & 1);
        __syncthreads();
    }

    const float M = Mp[0], yz = yzp[0];
    #pragma unroll
    for (int n = 0; n < 2; ++n) {
        const int col = n0 + wc * 32 + n * 16 + fr;
        const int bv = bias[col];
        #pragma unroll
        for (int m = 0; m < 4; ++m) {
            const int row = row0 + wr * 64 + m * 16 + fq * 4;
            float* yp = Y + (size_t)row * OUTF + col;
            #pragma unroll
            for (int j = 0; j < 4; ++j)
                yp[(size_t)j * OUTF] = rintf((float)(acc[m][n][j] + bv) * M + yz);
        }
    }
}

extern "C" void kernel_launch(void* const* d_in, const int* in_sizes, int n_in,
                              void* d_out, int out_size, void* d_ws, size_t ws_size,
                              hipStream_t stream) {
    const float* x    = (const float*)d_in[0];
    const int*   w    = (const int*)d_in[1];
    const int*   bias = (const int*)d_in[2];
    const float* M    = (const float*)d_in[3];
    const float* xz   = (const float*)d_in[4];
    const float* wz   = (const float*)d_in[5];
    const float* yz   = (const float*)d_in[6];
    float* y = (float*)d_out;

    unsigned char* Wb = (unsigned char*)d_ws;                 // 256 KB
    unsigned char* Xbp = Wb + 256 * 1024;                     // 32 MB
    const size_t need = 256 * 1024 + (size_t)65536 * 512;

    wprep<<<256, 256, 0, stream>>>(w, (unsigned int*)Wb, wz);

    if (ws_size >= need) {
        xprep<<<8192, 256, 0, stream>>>(x, (u32x4*)Xbp, xz);
        qgemm<<<2048, 256, 0, stream>>>(Xbp, Wb, bias, M, yz, y);
    } else {
        qgemm_fb<<<2048, 512, 0, stream>>>(x, Wb, bias, M, xz, yz, y);
    }
}